// Round 6
// baseline (44.644 us; speedup 1.0000x reference)
//
#include <hip/hip_runtime.h>
#include <hip/hip_bf16.h>

// ---- problem constants ----
#define BATCH  65536
#define KREAL  784          // 28*28 = GEMM-K (conv folded into Weff)
#define BK     64
#define NCHUNK 13
#define HID    128
#define NOUT   10
#define BM     64           // rows per block
#define NTHR   256          // 4 waves

using f32x4  = __attribute__((ext_vector_type(4))) float;
using short8 = __attribute__((ext_vector_type(8))) short;   // 8 bf16
using f4     = __attribute__((ext_vector_type(4))) float;

__device__ inline short f2b(float f) {
    union { __hip_bfloat16 h; short s; } u;
    u.h = __float2bfloat16(f);               // hardware RNE cvt
    return u.s;
}

// global -> LDS direct copy, 16 B per lane. gp: PER-LANE global addr,
// lp: wave-uniform LDS base (HW writes base + lane*16).
#define GLDS16(gp, lp) \
    __builtin_amdgcn_global_load_lds((const __attribute__((address_space(1))) void*)(gp), \
                                     (__attribute__((address_space(3))) void*)(lp), 16, 0, 0)

// ---------------------------------------------------------------------------
// Prep (unchanged from r5):
//  weff_sw[ic][r][cc] = Weff[r][ic*64 + ((cc>>3)^(r&7))*8 + (cc&7)]  (bf16)
//  w2f fragment-ordered: ((kk*4+hi)*16+lo)*8+e <-> w2[lo][kk*32+hi*8+e]
// ---------------------------------------------------------------------------
#define NWB (NCHUNK*HID*BK)   // 106496
#define NW2 (4*4*16*8)        // 2048

__global__ void prep_kernel(const float* __restrict__ conv_w,
                            const float* __restrict__ w1,
                            const float* __restrict__ w2,
                            unsigned short* __restrict__ weff_sw,
                            unsigned short* __restrict__ w2f)
{
    int idx = blockIdx.x * 256 + threadIdx.x;
    if (idx < NWB) {
        int ic  = idx >> 13;
        int rem = idx & 8191;
        int r   = rem >> 6;
        int cc  = rem & 63;
        int g   = (cc >> 3) ^ (r & 7);
        int k   = ic * BK + g * 8 + (cc & 7);
        float acc = 0.f;
        if (k < KREAL) {
            int rr = k / 28, c = k - rr * 28;
            #pragma unroll
            for (int di = 0; di < 3; ++di) {
                int i = rr - di;
                if (i >= 0 && i < 26) {
                    #pragma unroll
                    for (int dj = 0; dj < 3; ++dj) {
                        int j = c - dj;
                        if (j >= 0 && j < 26)
                            acc = fmaf(w1[r * 676 + i * 26 + j], conv_w[di * 3 + dj], acc);
                    }
                }
            }
        }
        weff_sw[idx] = (unsigned short)f2b(acc);
    } else {
        int k2 = idx - NWB;
        if (k2 < NW2) {
            int e  = k2 & 7;
            int lo = (k2 >> 3) & 15;
            int hi = (k2 >> 7) & 3;
            int kk = k2 >> 9;
            float v = (lo < NOUT) ? w2[lo * HID + kk * 32 + hi * 8 + e] : 0.f;
            w2f[k2] = (unsigned short)f2b(v);
        }
    }
}

// ---------------------------------------------------------------------------
// Fused: relu(x @ Weff^T + b1) @ w2^T + b2
// r5 structure + T4: bare s_barrier with COUNTED vmcnt(8) instead of
// __syncthreads' vmcnt(0) drain — prefetched chunk stays in flight across
// the barrier. Each wave issues exactly 8 global_load_lds per stage.
// ---------------------------------------------------------------------------
__global__ __launch_bounds__(NTHR, 2)
void fused_mlp_kernel(const float* __restrict__ x,
                      const float* __restrict__ b1,
                      const float* __restrict__ b2,
                      const unsigned short* __restrict__ weff_sw,
                      const unsigned short* __restrict__ w2f,
                      float* __restrict__ out)
{
    __shared__ __align__(16) unsigned char smem[65536];      // 64 KB
    float*          bufA0 = (float*)smem;                    // [64][64 fp32] swz
    float*          bufA1 = (float*)(smem + 16384);
    unsigned short* bufB0 = (unsigned short*)(smem + 32768); // [128][64 bf16] swz
    unsigned short* bufB1 = (unsigned short*)(smem + 49152);
    unsigned short* ldsH  = (unsigned short*)smem;           // [64][128] alias (per-wave slices)

    const int tid  = threadIdx.x;
    const int wv   = tid >> 6;
    const int lane = tid & 63;
    const int lo   = lane & 15;
    const int hi   = lane >> 4;
    const int row0 = blockIdx.x * BM;
    const int wr0  = wv * 16;

    f32x4 acc[8];
    #pragma unroll
    for (int t = 0; t < 8; ++t) acc[t] = (f32x4){0.f, 0.f, 0.f, 0.f};

    // A-stage: wave stages its OWN 16 rows; instr j covers rows wr0+j*4+hi,
    // lane granule gi=lo pre-swizzled to source granule gi^(j*4+hi).
    const char* abase = (const char*)(x + (long)(row0 + wr0 + hi) * KREAL);
    auto stageA = [&](int ic, float* dst) {
        #pragma unroll
        for (int j = 0; j < 4; ++j) {
            int sg = lo ^ (j * 4 + hi);              // source granule16 in row
            int ce = ic * BK + sg * 4;               // first fp32 col
            int cb = (ce < KREAL) ? ce : 0;          // clamp (chunk 12; B rows there are 0)
            GLDS16(abase + (long)j * 4 * KREAL * 4 + cb * 4,
                   (char*)dst + (wr0 + j * 4) * 256);
        }
    };
    auto stageB = [&](int ic, unsigned short* dst) {
        const char* src = (const char*)(weff_sw + (long)ic * (HID * BK));
        #pragma unroll
        for (int j = 0; j < 4; ++j)
            GLDS16(src + wv * 4096 + j * 1024 + lane * 16,
                   (char*)dst + wv * 4096 + j * 1024);
    };

    // ---- prologue: chunk 0 in flight (8 loads/wave) ----
    stageA(0, bufA0);
    stageB(0, bufB0);

    #pragma unroll
    for (int ic = 0; ic < NCHUNK; ++ic) {
        const float*          Ac = (ic & 1) ? bufA1 : bufA0;
        const unsigned short* Bc = (ic & 1) ? bufB1 : bufB0;
        if (ic + 1 < NCHUNK) {
            stageA(ic + 1, (ic & 1) ? bufA0 : bufA1);   // +8 loads -> 16 in flight
            stageB(ic + 1, (ic & 1) ? bufB0 : bufB1);
            asm volatile("s_waitcnt vmcnt(8)" ::: "memory");   // stage(ic) done
        } else {
            asm volatile("s_waitcnt vmcnt(0)" ::: "memory");
        }
        __builtin_amdgcn_s_barrier();                // all waves' stage(ic) landed
        __builtin_amdgcn_sched_barrier(0);           // no hoisting across the wait

        const int r = wr0 + lo;                      // this lane's A row
        #pragma unroll
        for (int kk = 0; kk < 2; ++kk) {
            const int G = kk * 4 + hi;               // 32B granule (8 fp32)
            f4 a0 = *(const f4*)((const char*)Ac + r * 256 + ((( 2 * G    ) ^ lo) << 4));
            f4 a1 = *(const f4*)((const char*)Ac + r * 256 + (((2 * G + 1) ^ lo) << 4));
            short8 af;
            #pragma unroll
            for (int e = 0; e < 4; ++e) {
                af[e]     = f2b(a0[e]);
                af[4 + e] = f2b(a1[e]);
            }
            #pragma unroll
            for (int t = 0; t < 8; ++t) {
                const int ob = t * 16 + lo;
                short8 bfrag = *(const short8*)&Bc[ob * BK + ((G ^ (ob & 7)) << 3)];
                acc[t] = __builtin_amdgcn_mfma_f32_16x16x32_bf16(af, bfrag, acc[t], 0, 0, 0);
            }
        }
        if (ic + 1 < NCHUNK) {
            __builtin_amdgcn_sched_barrier(0);       // reads above stay above
            __builtin_amdgcn_s_barrier();            // buffer free for next stage (no drain)
        }
    }

    // ---- FC1 epilogue: +b1, ReLU, h -> swizzled per-wave ldsH slice ----
    // No barrier: ldsH rows wr0..wr0+15 alias only this wave's bufA0 rows,
    // and per-wave DS ops are in-order.
    #pragma unroll
    for (int t = 0; t < 8; ++t) {
        float bias = b1[t * 16 + lo];
        #pragma unroll
        for (int j = 0; j < 4; ++j) {
            float hv = acc[t][j] + bias;
            hv = hv > 0.f ? hv : 0.f;
            int rloc = wr0 + hi * 4 + j;
            int col  = t * 16 + lo;
            int g    = col >> 3, e = col & 7;
            ldsH[rloc * HID + ((g ^ (rloc & 7)) << 3) + e] = (unsigned short)f2b(hv);
        }
    }

    // ---- FC2: h[16x128] @ w2^T[128x16] per wave, 4 MFMAs ----
    f32x4 acc2 = (f32x4){0.f, 0.f, 0.f, 0.f};
    #pragma unroll
    for (int kk = 0; kk < 4; ++kk) {
        int r = wr0 + lo;
        int g = kk * 4 + hi;
        short8 ha = *(const short8*)&ldsH[r * HID + ((g ^ (r & 7)) << 3)];
        short8 wb = *(const short8*)(w2f + (((kk * 4 + hi) * 16 + lo) << 3));
        acc2 = __builtin_amdgcn_mfma_f32_16x16x32_bf16(ha, wb, acc2, 0, 0, 0);
    }
    if (lo < NOUT) {
        float bb = b2[lo];
        #pragma unroll
        for (int j = 0; j < 4; ++j) {
            int grow = row0 + wr0 + hi * 4 + j;
            out[grow * NOUT + lo] = acc2[j] + bb;
        }
    }
}

// ---------------------------------------------------------------------------
extern "C" void kernel_launch(void* const* d_in, const int* in_sizes, int n_in,
                              void* d_out, int out_size, void* d_ws, size_t ws_size,
                              hipStream_t stream)
{
    const float* x      = (const float*)d_in[0];
    const float* conv_w = (const float*)d_in[1];
    const float* w1     = (const float*)d_in[2];
    const float* b1     = (const float*)d_in[3];
    const float* w2     = (const float*)d_in[4];
    const float* b2     = (const float*)d_in[5];
    float* out = (float*)d_out;

    unsigned short* weff_sw = (unsigned short*)d_ws;    // 106496 bf16
    unsigned short* w2f     = weff_sw + NWB;            // 2048 bf16

    const int prep_total = NWB + NW2;                   // 108544
    prep_kernel<<<(prep_total + 255) / 256, 256, 0, stream>>>(conv_w, w1, w2, weff_sw, w2f);
    fused_mlp_kernel<<<BATCH / BM, NTHR, 0, stream>>>(x, b1, b2, weff_sw, w2f, out);
}

// Round 7
// 43.675 us; speedup vs baseline: 1.0222x; 1.0222x over previous
//
#include <hip/hip_runtime.h>
#include <hip/hip_bf16.h>

// ---- problem constants ----
#define BATCH  65536
#define KREAL  784          // 28*28 = GEMM-K (conv folded into Weff)
#define BK     64
#define NCHUNK 13
#define HID    128
#define NOUT   10
#define BM     128          // rows per block
#define NTHR   512          // 8 waves; grid = 512 blocks = fully resident

using f32x4  = __attribute__((ext_vector_type(4))) float;
using short8 = __attribute__((ext_vector_type(8))) short;   // 8 bf16
using short4v= __attribute__((ext_vector_type(4))) short;   // 4 bf16 (8 B)
using f4     = __attribute__((ext_vector_type(4))) float;

__device__ inline short f2b(float f) {
    union { __hip_bfloat16 h; short s; } u;
    u.h = __float2bfloat16(f);               // hardware RNE cvt
    return u.s;
}

// global -> LDS direct copy, 16 B per lane. gp: PER-LANE global addr,
// lp: wave-uniform LDS base (HW writes base + lane*16).
#define GLDS16(gp, lp) \
    __builtin_amdgcn_global_load_lds((const __attribute__((address_space(1))) void*)(gp), \
                                     (__attribute__((address_space(3))) void*)(lp), 16, 0, 0)

// ---------------------------------------------------------------------------
// Prep (unchanged):
//  weff_sw[ic][r][cc] = Weff[r][ic*64 + ((cc>>3)^(r&7))*8 + (cc&7)]  (bf16)
//  w2f fragment-ordered: ((kk*4+hi)*16+lo)*8+e <-> w2[lo][kk*32+hi*8+e]
// ---------------------------------------------------------------------------
#define NWB (NCHUNK*HID*BK)   // 106496
#define NW2 (4*4*16*8)        // 2048

__global__ void prep_kernel(const float* __restrict__ conv_w,
                            const float* __restrict__ w1,
                            const float* __restrict__ w2,
                            unsigned short* __restrict__ weff_sw,
                            unsigned short* __restrict__ w2f)
{
    int idx = blockIdx.x * 256 + threadIdx.x;
    if (idx < NWB) {
        int ic  = idx >> 13;
        int rem = idx & 8191;
        int r   = rem >> 6;
        int cc  = rem & 63;
        int g   = (cc >> 3) ^ (r & 7);
        int k   = ic * BK + g * 8 + (cc & 7);
        float acc = 0.f;
        if (k < KREAL) {
            int rr = k / 28, c = k - rr * 28;
            #pragma unroll
            for (int di = 0; di < 3; ++di) {
                int i = rr - di;
                if (i >= 0 && i < 26) {
                    #pragma unroll
                    for (int dj = 0; dj < 3; ++dj) {
                        int j = c - dj;
                        if (j >= 0 && j < 26)
                            acc = fmaf(w1[r * 676 + i * 26 + j], conv_w[di * 3 + dj], acc);
                    }
                }
            }
        }
        weff_sw[idx] = (unsigned short)f2b(acc);
    } else {
        int k2 = idx - NWB;
        if (k2 < NW2) {
            int e  = k2 & 7;
            int lo = (k2 >> 3) & 15;
            int hi = (k2 >> 7) & 3;
            int kk = k2 >> 9;
            float v = (lo < NOUT) ? w2[lo * HID + kk * 32 + hi * 8 + e] : 0.f;
            w2f[k2] = (unsigned short)f2b(v);
        }
    }
}

// ---------------------------------------------------------------------------
// Fused: relu(x @ Weff^T + b1) @ w2^T + b2
// 512 blocks x 512 thr: whole grid co-resident (2 blocks/CU, 16 waves/CU).
// A: wave-private. Lane-linear f4 loads -> regs -> cvt -> swizzled ds_write
//    into the wave's own LDS slice (NO barrier needed for A, ever).
// B: pre-swizzled weff chunk via global_load_lds, double-buffered.
// ONE bare s_barrier per chunk; vmcnt(0) drain sits AFTER the compute
// overlap window.
// ---------------------------------------------------------------------------
__global__ __launch_bounds__(NTHR, 4)
void fused_mlp_kernel(const float* __restrict__ x,
                      const float* __restrict__ b1,
                      const float* __restrict__ b2,
                      const unsigned short* __restrict__ weff_sw,
                      const unsigned short* __restrict__ w2f,
                      float* __restrict__ out)
{
    __shared__ __align__(16) unsigned char smem[65536];      // 64 KB
    unsigned short* ldsA0 = (unsigned short*)smem;           // [128][64] bf16 swz
    unsigned short* ldsA1 = (unsigned short*)(smem + 16384);
    unsigned short* ldsB0 = (unsigned short*)(smem + 32768); // [128][64] bf16 swz
    unsigned short* ldsB1 = (unsigned short*)(smem + 49152);
    unsigned short* ldsH  = (unsigned short*)smem;           // [128][128] alias A0+A1
    float*          outS  = (float*)(smem + 49152);          // alias B1 (post-loop)

    const int tid  = threadIdx.x;
    const int wv   = tid >> 6;
    const int lane = tid & 63;
    const int lo   = lane & 15;
    const int hi   = lane >> 4;
    const int row0 = blockIdx.x * BM;
    const int wr0  = wv * 16;

    f32x4 acc[8];
    #pragma unroll
    for (int t = 0; t < 8; ++t) acc[t] = (f32x4){0.f, 0.f, 0.f, 0.f};

    // A: lane-linear loads. Instr j covers rows wr0+j*4+hi (4 rows x 256 B).
    const char* abase = (const char*)(x + (long)(row0 + wr0 + hi) * KREAL);
    f4 av[4];
    auto issueA = [&](int ic) {
        #pragma unroll
        for (int j = 0; j < 4; ++j) {
            int ce = ic * BK + lo * 4;
            int cb = (ce + 4 <= KREAL) ? ce : 0;   // clamp; B rows there are 0
            av[j] = *(const f4*)(abase + (long)j * 4 * KREAL * 4 + (long)cb * 4);
        }
    };
    // cvt + swizzled ds_write_b64 into the wave's OWN rows (wave-private).
    auto writeA = [&](unsigned short* dstA) {
        #pragma unroll
        for (int j = 0; j < 4; ++j) {
            int r = wr0 + j * 4 + hi;
            short4v c;
            c[0] = f2b(av[j][0]); c[1] = f2b(av[j][1]);
            c[2] = f2b(av[j][2]); c[3] = f2b(av[j][3]);
            int byteoff = r * 128 + ((((lo >> 1) ^ (r & 7)) << 4)) + ((lo & 1) << 3);
            *(short4v*)((char*)dstA + byteoff) = c;
        }
    };
    auto stageB = [&](int ic, unsigned short* dst) {
        const char* src = (const char*)(weff_sw + (long)ic * (HID * BK));
        GLDS16(src + wv * 2048 + lane * 16,        (char*)dst + wv * 2048);
        GLDS16(src + wv * 2048 + 1024 + lane * 16, (char*)dst + wv * 2048 + 1024);
    };

    // ---- prologue: chunk 0 ----
    issueA(0);
    stageB(0, ldsB0);
    asm volatile("s_waitcnt vmcnt(0)" ::: "memory");
    __builtin_amdgcn_sched_barrier(0);
    writeA(ldsA0);
    __builtin_amdgcn_s_barrier();                 // B0 visible to all waves
    __builtin_amdgcn_sched_barrier(0);

    #pragma unroll
    for (int ic = 0; ic < NCHUNK; ++ic) {
        const unsigned short* Ac = (ic & 1) ? ldsA1 : ldsA0;
        const unsigned short* Bc = (ic & 1) ? ldsB1 : ldsB0;
        if (ic + 1 < NCHUNK) {
            issueA(ic + 1);                       // -> regs (overlaps compute)
            stageB(ic + 1, (ic & 1) ? ldsB0 : ldsB1);  // safe: entry barrier
        }
        // compute chunk ic
        const int r = wr0 + lo;
        #pragma unroll
        for (int kk = 0; kk < 2; ++kk) {
            const int G = kk * 4 + hi;
            short8 af = *(const short8*)((const char*)Ac + r * 128 + ((G ^ (r & 7)) << 4));
            #pragma unroll
            for (int t = 0; t < 8; ++t) {
                const int ob = t * 16 + lo;
                short8 bfrag = *(const short8*)&Bc[ob * BK + ((G ^ (ob & 7)) << 3)];
                acc[t] = __builtin_amdgcn_mfma_f32_16x16x32_bf16(af, bfrag, acc[t], 0, 0, 0);
            }
        }
        if (ic + 1 < NCHUNK) {
            __builtin_amdgcn_sched_barrier(0);
            asm volatile("s_waitcnt vmcnt(0)" ::: "memory");  // A regs + B LDS landed
            __builtin_amdgcn_sched_barrier(0);
            writeA((ic & 1) ? ldsA0 : ldsA1);     // A(ic+1) -> opposite buffer
            __builtin_amdgcn_sched_barrier(0);
            __builtin_amdgcn_s_barrier();         // B(ic+1) visible; compute(ic) done everywhere
            __builtin_amdgcn_sched_barrier(0);
        }
    }

    __builtin_amdgcn_sched_barrier(0);
    __builtin_amdgcn_s_barrier();                 // all compute done before ldsH alias writes
    __builtin_amdgcn_sched_barrier(0);

    // ---- FC1 epilogue: +b1, ReLU, h -> swizzled per-wave ldsH slice ----
    // C/D layout: col = lane&15, row = (lane>>4)*4 + reg
    #pragma unroll
    for (int t = 0; t < 8; ++t) {
        float bias = b1[t * 16 + lo];
        #pragma unroll
        for (int j = 0; j < 4; ++j) {
            float hv = acc[t][j] + bias;
            hv = hv > 0.f ? hv : 0.f;
            int rloc = wr0 + hi * 4 + j;
            int col  = t * 16 + lo;
            int g    = col >> 3, e = col & 7;
            ldsH[rloc * HID + ((g ^ (rloc & 7)) << 3) + e] = (unsigned short)f2b(hv);
        }
    }
    // wave reads only its own writes below -> no barrier

    // ---- FC2: h[16x128] @ w2^T[128x16] per wave, 4 MFMAs ----
    f32x4 acc2 = (f32x4){0.f, 0.f, 0.f, 0.f};
    #pragma unroll
    for (int kk = 0; kk < 4; ++kk) {
        int r = wr0 + lo;
        int g = kk * 4 + hi;
        short8 ha = *(const short8*)&ldsH[r * HID + ((g ^ (r & 7)) << 3)];
        short8 wb = *(const short8*)(w2f + (((kk * 4 + hi) * 16 + lo) << 3));
        acc2 = __builtin_amdgcn_mfma_f32_16x16x32_bf16(ha, wb, acc2, 0, 0, 0);
    }
    // stage [16][10] f32 in the wave's outS slice, then one contiguous 640-B store
    float* os = outS + wv * 160;
    if (lo < NOUT) {
        float bb = b2[lo];
        #pragma unroll
        for (int j = 0; j < 4; ++j)
            os[(hi * 4 + j) * NOUT + lo] = acc2[j] + bb;
    }
    if (lane < 40) {
        f4 v = *(const f4*)&os[lane * 4];
        *(f4*)(out + (long)(row0 + wr0) * NOUT + lane * 4) = v;
    }
}

// ---------------------------------------------------------------------------
extern "C" void kernel_launch(void* const* d_in, const int* in_sizes, int n_in,
                              void* d_out, int out_size, void* d_ws, size_t ws_size,
                              hipStream_t stream)
{
    const float* x      = (const float*)d_in[0];
    const float* conv_w = (const float*)d_in[1];
    const float* w1     = (const float*)d_in[2];
    const float* b1     = (const float*)d_in[3];
    const float* w2     = (const float*)d_in[4];
    const float* b2     = (const float*)d_in[5];
    float* out = (float*)d_out;

    unsigned short* weff_sw = (unsigned short*)d_ws;    // 106496 bf16
    unsigned short* w2f     = weff_sw + NWB;            // 2048 bf16

    const int prep_total = NWB + NW2;                   // 108544
    prep_kernel<<<(prep_total + 255) / 256, 256, 0, stream>>>(conv_w, w1, w2, weff_sw, w2f);
    fused_mlp_kernel<<<BATCH / BM, NTHR, 0, stream>>>(x, b1, b2, weff_sw, w2f, out);
}